// Round 1
// 7470.702 us; speedup vs baseline: 1.0381x; 1.0381x over previous
//
#include <hip/hip_runtime.h>

// LSTM B=64, S=512, D=H=1024 on MI355X (gfx950).
// R4: batch-grouped persistent kernel. 2 independent recurrence groups
// (32 batches each) x 64 j-slices = 128 blocks x 1024 threads. Each block
// owns 64 gate-rows (16 j x 4 gates) with full K=2048 weights in VGPRs
// (16 waves = 4 K-quarters x 4 row-groups, 64 VGPRs of weights each).
// Per step:
//   phase1: x-waves (0-7)  : x MFMAs from xbf (L2-cached) -- no h dep,
//                            runs inside the h-wait window.
//           h-waves (8-15) : wave8 polls group counter (flat, monotonic,
//                            4B relaxed agent load) -> LDS flag fanout;
//                            then all 8 stage the group's 64 KB h into
//                            XOR-swizzled LDS (dense 512B sc1 reads).
//   SYNC0 ; phase2: h-waves ds_read_b128 frags + MFMA ; SYNC1
//   phase3: epilogue (512 thr): 4-way K-reduce from LDS, gates, state,
//           full-line out stores, shfl-packed u32 h-ring stores ; SYNC2
//   arrival: tid0 fetch_add on group counter (no tree, no release hop).
// Per-step L3 h traffic: 32 MB (R3) -> 8 MB. Syncs: 4 -> 3 per step.

typedef short short8 __attribute__((ext_vector_type(8)));
typedef float float4v __attribute__((ext_vector_type(4)));
typedef unsigned long long u64;

__device__ __forceinline__ short f2bf(float f) {
  union { float f; unsigned u; } v; v.f = f;
  unsigned r = (v.u + 0x7fffu + ((v.u >> 16) & 1u)) >> 16;  // RNE
  return (short)r;
}

__device__ __forceinline__ float sigm(float z) {
  float e = __expf(-fabsf(z));
  float p = 1.0f / (1.0f + e);
  return z >= 0.0f ? p : 1.0f - p;
}

__device__ __forceinline__ float tanh_s(float z) {
  float e = __expf(-2.0f * fabsf(z));
  float r = (1.0f - e) / (1.0f + e);
  return z >= 0.0f ? r : -r;
}

// one-time x fp32 [b][s][d] -> bf16 [s][b][d]
__global__ __launch_bounds__(256) void xconv(const float* __restrict__ x,
                                             short* __restrict__ xbf) {
  const int gid = blockIdx.x * 256 + threadIdx.x;
  const long i8 = (long)gid * 8;
  const int d  = (int)(i8 & 1023);
  const int bs = (int)(i8 >> 10);
  const int s  = bs & 511;
  const int b  = bs >> 9;
  const float4v* src = (const float4v*)(x + i8);
  float4v v0 = src[0], v1 = src[1];
  short8 o;
  o[0]=f2bf(v0[0]); o[1]=f2bf(v0[1]); o[2]=f2bf(v0[2]); o[3]=f2bf(v0[3]);
  o[4]=f2bf(v1[0]); o[5]=f2bf(v1[1]); o[6]=f2bf(v1[2]); o[7]=f2bf(v1[3]);
  *(short8*)(xbf + (((size_t)(s * 64 + b)) << 10) + d) = o;
}

template <bool XBF>
__global__ __launch_bounds__(1024, 4) void lstm_persist(
    const float* __restrict__ x, const short* __restrict__ xbf,
    const float* __restrict__ Wx, const float* __restrict__ bx,
    const float* __restrict__ Wh, const float* __restrict__ bh,
    float* __restrict__ out, unsigned* cnt, short* hbuf)
{
  __shared__ short hS[32 * 1024];      // 64 KB staged h, XOR-swizzled rows of 2 KB
  __shared__ float red[4][32][68];     // 34.8 KB [kq][batch][n], +4 pad vs 64
  __shared__ unsigned flag;            // release fanout

  const int tid  = threadIdx.x;
  const int bid  = blockIdx.x;
  const int g    = bid & 1;        // batch group (aligned with XCD parity)
  const int js   = bid >> 1;       // j-slice 0..63
  const int lane = tid & 63;
  const int w    = tid >> 6;       // wave 0..15
  const int kq   = w >> 2;         // K-quarter: 0,1 -> x, 2,3 -> h
  const int rg   = w & 3;          // row-group (16 rows each)
  const int l15  = lane & 15;
  const int lh   = lane >> 4;

  unsigned* cnt_g = cnt + g * 64;                 // own 256B line per group
  short* hb_g = hbuf + (size_t)g * 65536;         // 2 x 32 x 1024 bf16 ring

  // ---- static weights: 16 rows per wave, n = l15 = jj*4+gi ----
  short8 bw[16];
  {
    const int gi  = l15 & 3;
    const int jj  = l15 >> 2;
    const int row = gi * 1024 + js * 16 + rg * 4 + jj;
    const float* Wsrc = (kq < 2) ? (Wx + (size_t)row * 1024 + kq * 512)
                                 : (Wh + (size_t)row * 1024 + (kq - 2) * 512);
    #pragma unroll
    for (int ks = 0; ks < 16; ++ks) {
      const float* p = Wsrc + ks * 32 + lh * 8;
      float4v v0 = *(const float4v*)p;
      float4v v1 = *(const float4v*)(p + 4);
      short8 o;
      o[0]=f2bf(v0[0]); o[1]=f2bf(v0[1]); o[2]=f2bf(v0[2]); o[3]=f2bf(v0[3]);
      o[4]=f2bf(v1[0]); o[5]=f2bf(v1[1]); o[6]=f2bf(v1[2]); o[7]=f2bf(v1[3]);
      bw[ks] = o;
    }
  }

  // ---- epilogue identity: tid<512 owns (batch eb, hidden ejj) ----
  const int eb  = tid >> 4;        // 0..31 (block-local batch)
  const int ejj = tid & 15;        // 0..15 (block-local j)
  const int jg  = js * 16 + ejj;   // global j
  float bias[4] = {0.f, 0.f, 0.f, 0.f};
  if (tid < 512) {
    #pragma unroll
    for (int gi = 0; gi < 4; ++gi) bias[gi] = bx[gi * 1024 + jg] + bh[gi * 1024 + jg];
  }
  float c_reg = 0.0f, h_keep = 0.0f;

  if (tid == 0)
    __hip_atomic_store(&flag, 0u, __ATOMIC_RELAXED, __HIP_MEMORY_SCOPE_WORKGROUP);
  __syncthreads();

  char* const hSB = (char*)hS;

  for (int t = 0; t < 512; ++t) {
    float4v acc[2];
    acc[0] = (float4v){0.f, 0.f, 0.f, 0.f};
    acc[1] = (float4v){0.f, 0.f, 0.f, 0.f};

    if (kq < 2) {
      // ---- phase 1 (x-waves): x MFMAs, no h dependency ----
      if (XBF) {
        const short* xb = xbf + ((size_t)t << 16) + kq * 512 + lh * 8;
        #pragma unroll
        for (int ks = 0; ks < 16; ++ks) {
          #pragma unroll
          for (int mt = 0; mt < 2; ++mt) {
            const int b = g * 32 + mt * 16 + l15;
            short8 a = *(const short8*)(xb + ((size_t)b << 10) + ks * 32);
            acc[mt] = __builtin_amdgcn_mfma_f32_16x16x32_bf16(a, bw[ks], acc[mt], 0, 0, 0);
          }
        }
      } else {
        const float* Ab = x + (size_t)t * 1024 + kq * 512 + lh * 8;
        #pragma unroll
        for (int ks = 0; ks < 16; ++ks) {
          #pragma unroll
          for (int mt = 0; mt < 2; ++mt) {
            const int b = g * 32 + mt * 16 + l15;
            const float* p = Ab + (size_t)b * 524288 + ks * 32;
            float4v v0 = *(const float4v*)p;
            float4v v1 = *(const float4v*)(p + 4);
            short8 a;
            a[0]=f2bf(v0[0]); a[1]=f2bf(v0[1]); a[2]=f2bf(v0[2]); a[3]=f2bf(v0[3]);
            a[4]=f2bf(v1[0]); a[5]=f2bf(v1[1]); a[6]=f2bf(v1[2]); a[7]=f2bf(v1[3]);
            acc[mt] = __builtin_amdgcn_mfma_f32_16x16x32_bf16(a, bw[ks], acc[mt], 0, 0, 0);
          }
        }
      }
      #pragma unroll
      for (int mt = 0; mt < 2; ++mt)
        #pragma unroll
        for (int r = 0; r < 4; ++r)
          red[kq][mt * 16 + lh * 4 + r][rg * 16 + l15] = acc[mt][r];
    } else {
      // ---- phase 1 (h-waves): release detect + stage h into LDS ----
      if (w == 8) {
        const unsigned target = (unsigned)t * 64u;   // all 64 group blocks done step t-1
        while (__hip_atomic_load(cnt_g, __ATOMIC_RELAXED, __HIP_MEMORY_SCOPE_AGENT) < target)
          __builtin_amdgcn_s_sleep(2);
        if (lane == 0)
          __hip_atomic_store(&flag, (unsigned)(t + 1), __ATOMIC_RELAXED, __HIP_MEMORY_SCOPE_WORKGROUP);
      } else {
        while (__hip_atomic_load(&flag, __ATOMIC_RELAXED, __HIP_MEMORY_SCOPE_WORKGROUP) < (unsigned)(t + 1))
          __builtin_amdgcn_s_sleep(1);
      }
      // 512 threads stage 64 KB: dense 256B-per-16-lane sc1 reads
      const int tau = tid - 512;
      const int row = tau >> 4;          // 0..31
      const int sec = tau & 15;          // 0..15
      const short* src = hb_g + (size_t)(t & 1) * 32768 + row * 1024 + sec * 8;
      #pragma unroll
      for (int i = 0; i < 8; ++i) {
        const u64* p = (const u64*)(src + i * 128);
        union { u64 q[2]; short8 s; } u;
        u.q[0] = __hip_atomic_load(p,     __ATOMIC_RELAXED, __HIP_MEMORY_SCOPE_AGENT);
        u.q[1] = __hip_atomic_load(p + 1, __ATOMIC_RELAXED, __HIP_MEMORY_SCOPE_AGENT);
        const unsigned byte = (((unsigned)row << 11) + sec * 16 + i * 256)
                              ^ ((unsigned)(row & 7) << 4);
        *(short8*)(hSB + byte) = u.s;
      }
    }
    __syncthreads();   // SYNC0: h staged (x red already written)

    if (kq >= 2) {
      // ---- phase 2 (h-waves): swizzled ds_read_b128 frags + MFMA ----
      const unsigned cb = (unsigned)((kq - 2) * 1024 + lh * 16);
      const unsigned xr = (unsigned)((l15 & 7) << 4);
      #pragma unroll
      for (int ks = 0; ks < 16; ++ks) {
        #pragma unroll
        for (int mt = 0; mt < 2; ++mt) {
          const unsigned byte = (((unsigned)(mt * 16 + l15) << 11) + cb + ks * 64) ^ xr;
          short8 a = *(const short8*)(hSB + byte);
          acc[mt] = __builtin_amdgcn_mfma_f32_16x16x32_bf16(a, bw[ks], acc[mt], 0, 0, 0);
        }
      }
      #pragma unroll
      for (int mt = 0; mt < 2; ++mt)
        #pragma unroll
        for (int r = 0; r < 4; ++r)
          red[kq][mt * 16 + lh * 4 + r][rg * 16 + l15] = acc[mt][r];
    }
    __syncthreads();   // SYNC1: all partials in red

    if (tid < 512) {
      // ---- phase 3: K-reduce + gates + state + stores ----
      const int base = (ejj >> 2) * 16 + (ejj & 3) * 4;
      const float4v r0 = *(const float4v*)&red[0][eb][base];
      const float4v r1 = *(const float4v*)&red[1][eb][base];
      const float4v r2 = *(const float4v*)&red[2][eb][base];
      const float4v r3 = *(const float4v*)&red[3][eb][base];
      const float s0 = r0[0] + r1[0] + r2[0] + r3[0] + bias[0];
      const float s1 = r0[1] + r1[1] + r2[1] + r3[1] + bias[1];
      const float s2 = r0[2] + r1[2] + r2[2] + r3[2] + bias[2];
      const float s3 = r0[3] + r1[3] + r2[3] + r3[3] + bias[3];
      const float ig = sigm(s0);
      const float fg = sigm(s1);
      const float og = sigm(s2);
      const float gg = tanh_s(s3);
      c_reg = fg * c_reg + ig * gg;
      const float hh = og * tanh_s(c_reg);
      h_keep = hh;
      out[((size_t)(g * 32 + eb) * 512 + t) * 1024 + jg] = hh;   // 64B-line stores
      // pack 2 bf16 via shfl -> one u32 agent-scope store into next buffer
      unsigned hv = (unsigned)(unsigned short)f2bf(hh);
      unsigned nb = (unsigned)__shfl_xor((int)hv, 1, 64);
      if ((ejj & 1) == 0) {
        unsigned vv = hv | (nb << 16);
        unsigned* dst = (unsigned*)(hb_g + (size_t)((t + 1) & 1) * 32768 + eb * 1024 + jg);
        __hip_atomic_store(dst, vv, __ATOMIC_RELAXED, __HIP_MEMORY_SCOPE_AGENT);
      }
    }
    __syncthreads();   // SYNC2: drains h stores (vmcnt(0) before s_barrier)
    if (tid == 0)
      __hip_atomic_fetch_add(cnt_g, 1u, __ATOMIC_RELAXED, __HIP_MEMORY_SCOPE_AGENT);
  }

  if (tid < 512) {
    const size_t BSH = (size_t)64 * 512 * 1024;
    out[BSH + (size_t)(g * 32 + eb) * 1024 + jg] = h_keep;
    out[BSH + 65536 + (size_t)(g * 32 + eb) * 1024 + jg] = c_reg;
  }
}

extern "C" void kernel_launch(void* const* d_in, const int* in_sizes, int n_in,
                              void* d_out, int out_size, void* d_ws, size_t ws_size,
                              hipStream_t stream) {
  (void)in_sizes; (void)n_in; (void)out_size;
  const float* x  = (const float*)d_in[0];
  const float* Wx = (const float*)d_in[1];
  const float* bx = (const float*)d_in[2];
  const float* Wh = (const float*)d_in[3];
  const float* bh = (const float*)d_in[4];
  float* out = (float*)d_out;

  unsigned* cnt = (unsigned*)d_ws;                          // 1 KB counters (2 groups)
  short* hbuf   = (short*)((char*)d_ws + 1024);             // 2 groups x 2 x 64 KB h ring
  short* xbf    = (short*)((char*)d_ws + 1024 + 262144);    // 64 MB bf16 x [t][b][d]
  const size_t need_xbf = 1024u + 262144u + (size_t)64 * 512 * 1024 * 2;

  hipMemsetAsync(d_ws, 0, 1024 + 262144, stream);           // counters + h0 = 0

  if (ws_size >= need_xbf) {
    hipLaunchKernelGGL(xconv, dim3(16384), dim3(256), 0, stream, x, xbf);
    hipLaunchKernelGGL(lstm_persist<true>, dim3(128), dim3(1024), 0, stream,
                       x, xbf, Wx, bx, Wh, bh, out, cnt, hbuf);
  } else {
    hipLaunchKernelGGL(lstm_persist<false>, dim3(128), dim3(1024), 0, stream,
                       x, hbuf, Wx, bx, Wh, bh, out, cnt, hbuf);
  }
}